// Round 17
// baseline (113.852 us; speedup 1.0000x reference)
//
#include <hip/hip_runtime.h>
#include <hip/hip_bf16.h>

// NT-Xent loss, N=4096, D=256, T=0.5.
// loss = mean_r [ LSE_{c!=r}(2 z_r.z_c) - 2 z_r.z_label(r) ], z = concat(z_i,z_j) (8192x256)
// R21: full 256^2 template port (m198->m201 family), not another graft. R11-R20
// measured the m97-class ceiling (~890 TF) ten times under every graft. Now:
//  - 1024 blocks (32x32 tile grid) x 512 thr (8 waves, 2M x 4N). Tile 256x256.
//  - BK=32 -> 8 K-tiles; LDS 2buf x (A 16KB + B 16KB) = 64KB -> 2 blocks/CU.
//  - per K-tile/wave: 12 ds_read_b128 (swizzled) + 32 MFMA 16x16x32 into 32 named
//    f32x4 accs; schedule {vmcnt(4); barrier; reads+MFMA(setprio); barrier;
//    stage kt+2} -- loads span K-tiles (T3/T4), never drain mid-loop.
//  - T2 swizzle, both-sides-or-neither (rule 21): linear gload_lds dest +
//    inverse-swizzled GLOBAL src + swizzled ds_read: byte ^= ((row&3)<<4).
//  - symmetric GEMM (C = Z Z^T): A and B fragments load identically, no transpose.
//  - ONE epilogue (K accumulated fully): diag poison (br==bc blocks only,
//    verified layout from R20's passing run), 128 v_exp_f32, shfl-reduce over
//    lane&15, float4 stores to Lpart[128 col-chunks][8192].
// Zp is PLAIN row-major now (k_convert simplified).

typedef __bf16 bf16x8 __attribute__((ext_vector_type(8)));
typedef __bf16 bf16x4 __attribute__((ext_vector_type(4)));
typedef float  f32x4  __attribute__((ext_vector_type(4)));

#define NPAIR 4096
#define NROW  8192
#define DIM   256
#define NCHUNK 128                // Lpart col-chunks of 64
// x = dot/T * log2(e) = dot * 2*log2(e); Z pre-scaled by sqrt(2*log2 e)
#define SQSCALE 1.6986437f
#define LN2F    0.6931471805599453f
#define M2      176.0f            // fixed LSE max (log2 units); validated R5

#define EXP2F(x) __builtin_amdgcn_exp2f(x)   // raw v_exp_f32

// ---------- kernel 1: f32 -> bf16 (pre-scaled) plain row-major + pos + out zero ----
__global__ __launch_bounds__(256) void k_convert(const float* __restrict__ zi,
                                                 const float* __restrict__ zj,
                                                 __bf16* __restrict__ Zp,
                                                 float* __restrict__ pos,
                                                 float* __restrict__ out) {
    const int w = threadIdx.x >> 6, lane = threadIdx.x & 63;
    const int r = blockIdx.x * 4 + w;
    if (blockIdx.x == 0 && threadIdx.x == 0) out[0] = 0.0f;
    const float4 vi = *(const float4*)(zi + r * DIM + lane * 4);
    const float4 vj = *(const float4*)(zj + r * DIM + lane * 4);
    bf16x4 bi, bj;
    bi[0] = (__bf16)(vi.x * SQSCALE); bi[1] = (__bf16)(vi.y * SQSCALE);
    bi[2] = (__bf16)(vi.z * SQSCALE); bi[3] = (__bf16)(vi.w * SQSCALE);
    bj[0] = (__bf16)(vj.x * SQSCALE); bj[1] = (__bf16)(vj.y * SQSCALE);
    bj[2] = (__bf16)(vj.z * SQSCALE); bj[3] = (__bf16)(vj.w * SQSCALE);
    char* Zb = (char*)Zp;
    *(bf16x4*)(Zb + (size_t)r * 512 + lane * 8) = bi;                 // row r
    *(bf16x4*)(Zb + (size_t)(r + NPAIR) * 512 + lane * 8) = bj;       // row r+N
    float d = vi.x * vj.x + vi.y * vj.y + vi.z * vj.z + vi.w * vj.w;
    #pragma unroll
    for (int m = 32; m >= 1; m >>= 1) d += __shfl_xor(d, m);
    if (lane == 0) pos[r] = 2.0f * d;   // natural units
}

// ---------- kernel 2: 256x256-tile LSE-GEMM, 8-wave template ----------
__global__ __launch_bounds__(512, 2) void k_lse(const __bf16* __restrict__ Zp,
                                                float* __restrict__ Lpart) {
    const int bid = blockIdx.x;
    const int br = bid >> 5, bc = bid & 31;        // consecutive bids share br -> XCD A-reuse
    const int tid = threadIdx.x;
    const int w = tid >> 6, lane = tid & 63;
    const int wr = w >> 2, wc = w & 3;             // 2M x 4N wave grid
    const int l15 = lane & 15, l4 = lane >> 4;

    __shared__ __align__(16) char smem[65536];     // 2 x (A 16KB + B 16KB)
    const char* Zb = (const char*)Zp;
    const int arow0 = br * 256, brow0 = bc * 256;

    // swizzled per-thread ds_read bases: addr = row*64 + ((l4*16) ^ ((row&3)<<4));
    // row&3 == lane&3 for all our frag rows (bases are multiples of 16).
    const int j16sw = (l4 * 16) ^ ((lane & 3) << 4);
    const int aBase = (wr * 128 + l15) * 64 + j16sw;
    const int bBase = (wc * 64  + l15) * 64 + j16sw;

    // stage K-tile KT (K cols KT*32..+32) into buf KT&1: linear LDS dest,
    // inverse-swizzled global source (rule 21; self-inverse XOR).
    #define STAGE(KT) do {                                                           \
        char* db = smem + ((KT) & 1) * 32768;                                        \
        _Pragma("unroll")                                                            \
        for (int q = 0; q < 2; q++) {                                                \
            const int c = q * 512 + tid;                                             \
            const int row = c >> 2;                                                  \
            const int inner = ((c & 3) * 16) ^ ((row & 3) << 4);                     \
            __builtin_amdgcn_global_load_lds(                                        \
                (const __attribute__((address_space(1))) unsigned int*)              \
                    (Zb + (size_t)(arow0 + row) * 512 + (KT) * 64 + inner),          \
                (__attribute__((address_space(3))) unsigned int*)(db + c * 16),      \
                16, 0, 0);                                                           \
        }                                                                            \
        _Pragma("unroll")                                                            \
        for (int q = 0; q < 2; q++) {                                                \
            const int c = q * 512 + tid;                                             \
            const int row = c >> 2;                                                  \
            const int inner = ((c & 3) * 16) ^ ((row & 3) << 4);                     \
            __builtin_amdgcn_global_load_lds(                                        \
                (const __attribute__((address_space(1))) unsigned int*)              \
                    (Zb + (size_t)(brow0 + row) * 512 + (KT) * 64 + inner),          \
                (__attribute__((address_space(3))) unsigned int*)(db + 16384 + c * 16), \
                16, 0, 0);                                                           \
        }                                                                            \
    } while (0)

    // 32 named accumulators c<mt><nt>
    #define DECL(M) f32x4 c##M##0 = (f32x4)(0.0f), c##M##1 = (f32x4)(0.0f), \
                          c##M##2 = (f32x4)(0.0f), c##M##3 = (f32x4)(0.0f);
    DECL(0) DECL(1) DECL(2) DECL(3) DECL(4) DECL(5) DECL(6) DECL(7)
    #undef DECL

    STAGE(0);
    STAGE(1);

    #define MROW(M, AF) \
        c##M##0 = __builtin_amdgcn_mfma_f32_16x16x32_bf16(AF, b0, c##M##0, 0, 0, 0); \
        c##M##1 = __builtin_amdgcn_mfma_f32_16x16x32_bf16(AF, b1, c##M##1, 0, 0, 0); \
        c##M##2 = __builtin_amdgcn_mfma_f32_16x16x32_bf16(AF, b2, c##M##2, 0, 0, 0); \
        c##M##3 = __builtin_amdgcn_mfma_f32_16x16x32_bf16(AF, b3, c##M##3, 0, 0, 0);

    for (int kt = 0; kt < 8; ++kt) {
        if (kt < 7) { asm volatile("s_waitcnt vmcnt(4)" ::: "memory"); }  // own tile landed, next flying
        else        { asm volatile("s_waitcnt vmcnt(0)" ::: "memory"); }
        __builtin_amdgcn_s_barrier();          // all threads' stage loads landed
        const char* Ab = smem + (kt & 1) * 32768;
        const char* Bb = Ab + 16384;
        bf16x8 a0 = *(const bf16x8*)(Ab + aBase + 0 * 1024);
        bf16x8 a1 = *(const bf16x8*)(Ab + aBase + 1 * 1024);
        bf16x8 a2 = *(const bf16x8*)(Ab + aBase + 2 * 1024);
        bf16x8 a3 = *(const bf16x8*)(Ab + aBase + 3 * 1024);
        bf16x8 a4 = *(const bf16x8*)(Ab + aBase + 4 * 1024);
        bf16x8 a5 = *(const bf16x8*)(Ab + aBase + 5 * 1024);
        bf16x8 a6 = *(const bf16x8*)(Ab + aBase + 6 * 1024);
        bf16x8 a7 = *(const bf16x8*)(Ab + aBase + 7 * 1024);
        bf16x8 b0 = *(const bf16x8*)(Bb + bBase + 0 * 1024);
        bf16x8 b1 = *(const bf16x8*)(Bb + bBase + 1 * 1024);
        bf16x8 b2 = *(const bf16x8*)(Bb + bBase + 2 * 1024);
        bf16x8 b3 = *(const bf16x8*)(Bb + bBase + 3 * 1024);
        __builtin_amdgcn_s_setprio(1);
        MROW(0, a0) MROW(1, a1) MROW(2, a2) MROW(3, a3)
        MROW(4, a4) MROW(5, a5) MROW(6, a6) MROW(7, a7)
        __builtin_amdgcn_s_setprio(0);
        __builtin_amdgcn_s_barrier();          // all waves done reading this buffer
        if (kt < 6) STAGE(kt + 2);             // overwrite just-freed buffer
    }
    #undef MROW
    #undef STAGE

    // ---- epilogue (once): diag poison, exp2, col-reduce, store partials ----
    // D layout (verified by R20 pass): row (A-side) = l4*4 + reg, col (B-side) = l15.
    const bool diagblk = (br == bc);
    const bool dlane = (l15 >> 2) == l4;
    const int dreg = lane & 3;
    float* Lp = Lpart + (size_t)(bc * 4 + wc) * NROW + arow0 + wr * 128;

    #define EPIT(MT, NT) {                                                           \
        f32x4 v = c##MT##NT;                                                         \
        const bool dp = diagblk && dlane && (wr * 128 + (MT) * 16 == wc * 64 + (NT) * 16); \
        r0 += EXP2F(((dp && dreg == 0) ? -1e30f : v[0]) - M2);                       \
        r1 += EXP2F(((dp && dreg == 1) ? -1e30f : v[1]) - M2);                       \
        r2 += EXP2F(((dp && dreg == 2) ? -1e30f : v[2]) - M2);                       \
        r3 += EXP2F(((dp && dreg == 3) ? -1e30f : v[3]) - M2);                       \
    }
    #define EPI(MT) {                                                                \
        float r0 = 0.0f, r1 = 0.0f, r2 = 0.0f, r3 = 0.0f;                            \
        EPIT(MT, 0) EPIT(MT, 1) EPIT(MT, 2) EPIT(MT, 3)                              \
        r0 += __shfl_xor(r0, 1); r0 += __shfl_xor(r0, 2);                            \
        r0 += __shfl_xor(r0, 4); r0 += __shfl_xor(r0, 8);                            \
        r1 += __shfl_xor(r1, 1); r1 += __shfl_xor(r1, 2);                            \
        r1 += __shfl_xor(r1, 4); r1 += __shfl_xor(r1, 8);                            \
        r2 += __shfl_xor(r2, 1); r2 += __shfl_xor(r2, 2);                            \
        r2 += __shfl_xor(r2, 4); r2 += __shfl_xor(r2, 8);                            \
        r3 += __shfl_xor(r3, 1); r3 += __shfl_xor(r3, 2);                            \
        r3 += __shfl_xor(r3, 4); r3 += __shfl_xor(r3, 8);                            \
        if (l15 == 0) *(float4*)(Lp + (MT) * 16 + l4 * 4) = make_float4(r0, r1, r2, r3); \
    }
    EPI(0) EPI(1) EPI(2) EPI(3) EPI(4) EPI(5) EPI(6) EPI(7)
    #undef EPI
    #undef EPIT
}

// ---------- kernel 3: merge col-chunks, per-row loss, atomic mean ----------
__global__ __launch_bounds__(256) void k_final(const float* __restrict__ Lpart,
                                               const float* __restrict__ pos,
                                               float* __restrict__ out) {
    __shared__ float red[256];
    const int t = threadIdx.x;
    const int r = blockIdx.x * 256 + t;
    float l = 0.0f;
    #pragma unroll 8
    for (int s = 0; s < NCHUNK; s++) l += Lpart[(size_t)s * NROW + r];
    const float lse = (M2 + __builtin_log2f(l)) * LN2F;   // natural-log LSE
    red[t] = lse - pos[r & (NPAIR - 1)];
    __syncthreads();
    for (int ofs = 128; ofs > 0; ofs >>= 1) {
        if (t < ofs) red[t] += red[t + ofs];
        __syncthreads();
    }
    if (t == 0) atomicAdd(out, red[0] / (float)NROW);
}

extern "C" void kernel_launch(void* const* d_in, const int* in_sizes, int n_in,
                              void* d_out, int out_size, void* d_ws, size_t ws_size,
                              hipStream_t stream) {
    const float* zi = (const float*)d_in[0];
    const float* zj = (const float*)d_in[1];
    __bf16* Zp   = (__bf16*)d_ws;                       // 4 MB plain row-major
    float* pos   = (float*)((char*)d_ws + (size_t)NROW * DIM * 2);
    float* Lpart = pos + NPAIR;                         // 128 x 8192 floats (4 MB)

    k_convert<<<NPAIR / 4, 256, 0, stream>>>(zi, zj, Zp, pos, (float*)d_out);
    k_lse<<<32 * 32, 512, 0, stream>>>(Zp, Lpart);
    k_final<<<NROW / 256, 256, 0, stream>>>(Lpart, pos, (float*)d_out);
}

// Round 18
// 111.091 us; speedup vs baseline: 1.0249x; 1.0249x over previous
//
#include <hip/hip_runtime.h>
#include <hip/hip_bf16.h>

// NT-Xent loss, N=4096, D=256, T=0.5.
// loss = mean_r [ LSE_{c!=r}(2 z_r.z_c) - 2 z_r.z_label(r) ], z = concat(z_i,z_j) (8192x256)
// R22 = R21 (verified-correct 256^2 template) with its two measured flaws fixed:
//  1) bank conflicts (3.1M): swizzle bits were (row&3) -> lanes {0,4,8,12} alias
//     (4-way). Correct: ((row>>1)&3)<<4 -> 8 banks, 2-way = free.
//  2) 1 block/CU (occupancy 20%) + coarse [reads][MFMA] per kt -> LDS pipe and
//     matrix pipe alternate serially. Fix: 2 software-pipelined half-phases/kt --
//     reads of half p+1 issued BEFORE MFMA of half p (cross-kt: B double-buffered
//     bP/bQ; a0-3 freed by half0's MFMA), so LDS serves next reads UNDER the
//     16-MFMA cluster. lgkmcnt(0) before the STAGE-guarding barrier (pending
//     reads must retire before buffer overwrite); counted vmcnt(4) mid-kt.
// Geometry unchanged: 1024 blocks (32x32) x 512 thr (8 waves 2Mx4N), tile 256^2,
// BK=32, 8 kt, LDS 2x32KB, ~217 regs (acc 128 + 16 frags), symmetric GEMM.

typedef __bf16 bf16x8 __attribute__((ext_vector_type(8)));
typedef __bf16 bf16x4 __attribute__((ext_vector_type(4)));
typedef float  f32x4  __attribute__((ext_vector_type(4)));

#define NPAIR 4096
#define NROW  8192
#define DIM   256
#define NCHUNK 128                // Lpart col-chunks of 64
// x = dot/T * log2(e) = dot * 2*log2(e); Z pre-scaled by sqrt(2*log2 e)
#define SQSCALE 1.6986437f
#define LN2F    0.6931471805599453f
#define M2      176.0f            // fixed LSE max (log2 units); validated R5

#define EXP2F(x) __builtin_amdgcn_exp2f(x)   // raw v_exp_f32

// ---------- kernel 1: f32 -> bf16 (pre-scaled) plain row-major + pos + out zero ----
__global__ __launch_bounds__(256) void k_convert(const float* __restrict__ zi,
                                                 const float* __restrict__ zj,
                                                 __bf16* __restrict__ Zp,
                                                 float* __restrict__ pos,
                                                 float* __restrict__ out) {
    const int w = threadIdx.x >> 6, lane = threadIdx.x & 63;
    const int r = blockIdx.x * 4 + w;
    if (blockIdx.x == 0 && threadIdx.x == 0) out[0] = 0.0f;
    const float4 vi = *(const float4*)(zi + r * DIM + lane * 4);
    const float4 vj = *(const float4*)(zj + r * DIM + lane * 4);
    bf16x4 bi, bj;
    bi[0] = (__bf16)(vi.x * SQSCALE); bi[1] = (__bf16)(vi.y * SQSCALE);
    bi[2] = (__bf16)(vi.z * SQSCALE); bi[3] = (__bf16)(vi.w * SQSCALE);
    bj[0] = (__bf16)(vj.x * SQSCALE); bj[1] = (__bf16)(vj.y * SQSCALE);
    bj[2] = (__bf16)(vj.z * SQSCALE); bj[3] = (__bf16)(vj.w * SQSCALE);
    char* Zb = (char*)Zp;
    *(bf16x4*)(Zb + (size_t)r * 512 + lane * 8) = bi;                 // row r
    *(bf16x4*)(Zb + (size_t)(r + NPAIR) * 512 + lane * 8) = bj;       // row r+N
    float d = vi.x * vj.x + vi.y * vj.y + vi.z * vj.z + vi.w * vj.w;
    #pragma unroll
    for (int m = 32; m >= 1; m >>= 1) d += __shfl_xor(d, m);
    if (lane == 0) pos[r] = 2.0f * d;   // natural units
}

// ---------- kernel 2: 256x256-tile LSE-GEMM, phase-pipelined 8-wave template ----------
__global__ __launch_bounds__(512, 2) void k_lse(const __bf16* __restrict__ Zp,
                                                float* __restrict__ Lpart) {
    const int bid = blockIdx.x;
    const int br = bid >> 5, bc = bid & 31;
    const int tid = threadIdx.x;
    const int w = tid >> 6, lane = tid & 63;
    const int wr = w >> 2, wc = w & 3;             // 2M x 4N wave grid
    const int l15 = lane & 15, l4 = lane >> 4;

    __shared__ __align__(16) char smem[65536];     // 2 x (A 16KB + B 16KB)
    const char* Zb = (const char*)Zp;
    const int arow0 = br * 256, brow0 = bc * 256;

    // conflict-free swizzle: byte ^= ((row>>1)&3)<<4 (row = base+l15, base%16==0)
    // -> bank = 16*(l15&1) + 4*(l4 ^ ((l15>>1)&3)): 8 banks, 2-way = free.
    const int j16sw = (l4 * 16) ^ (((l15 >> 1) & 3) << 4);
    const int aBase = (wr * 128 + l15) * 64 + j16sw;
    const int bBase = (wc * 64  + l15) * 64 + j16sw;

    // stage K-tile KT into buf KT&1: linear LDS dest, inverse-swizzled global src.
    #define STAGE(KT) do {                                                           \
        char* db = smem + ((KT) & 1) * 32768;                                        \
        _Pragma("unroll")                                                            \
        for (int q = 0; q < 2; q++) {                                                \
            const int c = q * 512 + tid;                                             \
            const int row = c >> 2;                                                  \
            const int inner = ((c & 3) * 16) ^ (((c >> 3) & 3) << 4);                \
            __builtin_amdgcn_global_load_lds(                                        \
                (const __attribute__((address_space(1))) unsigned int*)              \
                    (Zb + (size_t)(arow0 + row) * 512 + (KT) * 64 + inner),          \
                (__attribute__((address_space(3))) unsigned int*)(db + c * 16),      \
                16, 0, 0);                                                           \
        }                                                                            \
        _Pragma("unroll")                                                            \
        for (int q = 0; q < 2; q++) {                                                \
            const int c = q * 512 + tid;                                             \
            const int row = c >> 2;                                                  \
            const int inner = ((c & 3) * 16) ^ (((c >> 3) & 3) << 4);                \
            __builtin_amdgcn_global_load_lds(                                        \
                (const __attribute__((address_space(1))) unsigned int*)              \
                    (Zb + (size_t)(brow0 + row) * 512 + (KT) * 64 + inner),          \
                (__attribute__((address_space(3))) unsigned int*)(db + 16384 + c * 16), \
                16, 0, 0);                                                           \
        }                                                                            \
    } while (0)

    // 32 named accumulators c<mt><nt>
    #define DECL(M) f32x4 c##M##0 = (f32x4)(0.0f), c##M##1 = (f32x4)(0.0f), \
                          c##M##2 = (f32x4)(0.0f), c##M##3 = (f32x4)(0.0f);
    DECL(0) DECL(1) DECL(2) DECL(3) DECL(4) DECL(5) DECL(6) DECL(7)
    #undef DECL

    bf16x8 a0, a1, a2, a3, a4, a5, a6, a7;
    bf16x8 bP0, bP1, bP2, bP3, bQ0, bQ1, bQ2, bQ3;

    #define MROW(M, AF, BS) \
        c##M##0 = __builtin_amdgcn_mfma_f32_16x16x32_bf16(AF, b##BS##0, c##M##0, 0, 0, 0); \
        c##M##1 = __builtin_amdgcn_mfma_f32_16x16x32_bf16(AF, b##BS##1, c##M##1, 0, 0, 0); \
        c##M##2 = __builtin_amdgcn_mfma_f32_16x16x32_bf16(AF, b##BS##2, c##M##2, 0, 0, 0); \
        c##M##3 = __builtin_amdgcn_mfma_f32_16x16x32_bf16(AF, b##BS##3, c##M##3, 0, 0, 0);

    // prologue: 2 tiles staged; wait kt0 (4 of 8), load half0 frags of kt0
    STAGE(0);
    STAGE(1);
    asm volatile("s_waitcnt vmcnt(4)" ::: "memory");
    __builtin_amdgcn_s_barrier();
    {
        const char* Ab = smem;
        const char* Bb = Ab + 16384;
        a0 = *(const bf16x8*)(Ab + aBase + 0 * 1024);
        a1 = *(const bf16x8*)(Ab + aBase + 1 * 1024);
        a2 = *(const bf16x8*)(Ab + aBase + 2 * 1024);
        a3 = *(const bf16x8*)(Ab + aBase + 3 * 1024);
        bP0 = *(const bf16x8*)(Bb + bBase + 0 * 1024);
        bP1 = *(const bf16x8*)(Bb + bBase + 1 * 1024);
        bP2 = *(const bf16x8*)(Bb + bBase + 2 * 1024);
        bP3 = *(const bf16x8*)(Bb + bBase + 3 * 1024);
    }

    // one kt, software-pipelined: issue half1 reads; MFMA half0 (overlaps them);
    // lgkm-drain + barrier; STAGE kt+2 (buffer provably consumed); vmcnt(4) +
    // barrier (kt+1 landed, kt+2 flying); issue kt+1 half0 reads (other B set);
    // MFMA half1 (overlaps them).
    #define KTBODY(KT, BC, BN, WS) {                                                 \
        const char* Ab = smem + ((KT) & 1) * 32768;                                  \
        a4 = *(const bf16x8*)(Ab + aBase + 4 * 1024);                                \
        a5 = *(const bf16x8*)(Ab + aBase + 5 * 1024);                                \
        a6 = *(const bf16x8*)(Ab + aBase + 6 * 1024);                                \
        a7 = *(const bf16x8*)(Ab + aBase + 7 * 1024);                                \
        __builtin_amdgcn_s_setprio(1);                                               \
        MROW(0, a0, BC) MROW(1, a1, BC) MROW(2, a2, BC) MROW(3, a3, BC)              \
        __builtin_amdgcn_s_setprio(0);                                               \
        asm volatile("s_waitcnt lgkmcnt(0)" ::: "memory");  /* a4-7 retired */       \
        __builtin_amdgcn_s_barrier();                                                \
        if ((KT) < 6) STAGE((KT) + 2);                                               \
        if ((KT) < 7) {                                                              \
            asm volatile("s_waitcnt vmcnt(" WS ")" ::: "memory");                    \
            __builtin_amdgcn_s_barrier();                                            \
            const char* Ab2 = smem + (((KT) + 1) & 1) * 32768;                       \
            const char* Bb2 = Ab2 + 16384;                                           \
            a0 = *(const bf16x8*)(Ab2 + aBase + 0 * 1024);                           \
            a1 = *(const bf16x8*)(Ab2 + aBase + 1 * 1024);                           \
            a2 = *(const bf16x8*)(Ab2 + aBase + 2 * 1024);                           \
            a3 = *(const bf16x8*)(Ab2 + aBase + 3 * 1024);                           \
            b##BN##0 = *(const bf16x8*)(Bb2 + bBase + 0 * 1024);                     \
            b##BN##1 = *(const bf16x8*)(Bb2 + bBase + 1 * 1024);                     \
            b##BN##2 = *(const bf16x8*)(Bb2 + bBase + 2 * 1024);                     \
            b##BN##3 = *(const bf16x8*)(Bb2 + bBase + 3 * 1024);                     \
        }                                                                            \
        __builtin_amdgcn_s_setprio(1);                                               \
        MROW(4, a4, BC) MROW(5, a5, BC) MROW(6, a6, BC) MROW(7, a7, BC)              \
        __builtin_amdgcn_s_setprio(0);                                               \
    }

    KTBODY(0, P, Q, "4")
    KTBODY(1, Q, P, "4")
    KTBODY(2, P, Q, "4")
    KTBODY(3, Q, P, "4")
    KTBODY(4, P, Q, "4")
    KTBODY(5, Q, P, "4")
    KTBODY(6, P, Q, "0")   // no STAGE(8); waits kt7's 4 loads (1-kt margin)
    KTBODY(7, Q, P, "0")   // tail: no next reads
    #undef KTBODY
    #undef MROW
    #undef STAGE

    // ---- epilogue (verified in R21): diag poison, exp2, col-reduce, store ----
    // D layout: row (A-side) = l4*4 + reg, col (B-side) = l15.
    const bool diagblk = (br == bc);
    const bool dlane = (l15 >> 2) == l4;
    const int dreg = lane & 3;
    float* Lp = Lpart + (size_t)(bc * 4 + wc) * NROW + arow0 + wr * 128;

    #define EPIT(MT, NT) {                                                           \
        f32x4 v = c##MT##NT;                                                         \
        const bool dp = diagblk && dlane && (wr * 128 + (MT) * 16 == wc * 64 + (NT) * 16); \
        r0 += EXP2F(((dp && dreg == 0) ? -1e30f : v[0]) - M2);                       \
        r1 += EXP2F(((dp && dreg == 1) ? -1e30f : v[1]) - M2);                       \
        r2 += EXP2F(((dp && dreg == 2) ? -1e30f : v[2]) - M2);                       \
        r3 += EXP2F(((dp && dreg == 3) ? -1e30f : v[3]) - M2);                       \
    }
    #define EPI(MT) {                                                                \
        float r0 = 0.0f, r1 = 0.0f, r2 = 0.0f, r3 = 0.0f;                            \
        EPIT(MT, 0) EPIT(MT, 1) EPIT(MT, 2) EPIT(MT, 3)                              \
        r0 += __shfl_xor(r0, 1); r0 += __shfl_xor(r0, 2);                            \
        r0 += __shfl_xor(r0, 4); r0 += __shfl_xor(r0, 8);                            \
        r1 += __shfl_xor(r1, 1); r1 += __shfl_xor(r1, 2);                            \
        r1 += __shfl_xor(r1, 4); r1 += __shfl_xor(r1, 8);                            \
        r2 += __shfl_xor(r2, 1); r2 += __shfl_xor(r2, 2);                            \
        r2 += __shfl_xor(r2, 4); r2 += __shfl_xor(r2, 8);                            \
        r3 += __shfl_xor(r3, 1); r3 += __shfl_xor(r3, 2);                            \
        r3 += __shfl_xor(r3, 4); r3 += __shfl_xor(r3, 8);                            \
        if (l15 == 0) *(float4*)(Lp + (MT) * 16 + l4 * 4) = make_float4(r0, r1, r2, r3); \
    }
    EPI(0) EPI(1) EPI(2) EPI(3) EPI(4) EPI(5) EPI(6) EPI(7)
    #undef EPI
    #undef EPIT
}

// ---------- kernel 3: merge col-chunks, per-row loss, atomic mean ----------
__global__ __launch_bounds__(256) void k_final(const float* __restrict__ Lpart,
                                               const float* __restrict__ pos,
                                               float* __restrict__ out) {
    __shared__ float red[256];
    const int t = threadIdx.x;
    const int r = blockIdx.x * 256 + t;
    float l = 0.0f;
    #pragma unroll 8
    for (int s = 0; s < NCHUNK; s++) l += Lpart[(size_t)s * NROW + r];
    const float lse = (M2 + __builtin_log2f(l)) * LN2F;   // natural-log LSE
    red[t] = lse - pos[r & (NPAIR - 1)];
    __syncthreads();
    for (int ofs = 128; ofs > 0; ofs >>= 1) {
        if (t < ofs) red[t] += red[t + ofs];
        __syncthreads();
    }
    if (t == 0) atomicAdd(out, red[0] / (float)NROW);
}

extern "C" void kernel_launch(void* const* d_in, const int* in_sizes, int n_in,
                              void* d_out, int out_size, void* d_ws, size_t ws_size,
                              hipStream_t stream) {
    const float* zi = (const float*)d_in[0];
    const float* zj = (const float*)d_in[1];
    __bf16* Zp   = (__bf16*)d_ws;                       // 4 MB plain row-major
    float* pos   = (float*)((char*)d_ws + (size_t)NROW * DIM * 2);
    float* Lpart = pos + NPAIR;                         // 128 x 8192 floats (4 MB)

    k_convert<<<NPAIR / 4, 256, 0, stream>>>(zi, zj, Zp, pos, (float*)d_out);
    k_lse<<<32 * 32, 512, 0, stream>>>(Zp, Lpart);
    k_final<<<NROW / 256, 256, 0, stream>>>(Lpart, pos, (float*)d_out);
}

// Round 19
// 95.536 us; speedup vs baseline: 1.1917x; 1.1628x over previous
//
#include <hip/hip_runtime.h>
#include <hip/hip_bf16.h>

// NT-Xent loss, N=4096, D=256, T=0.5.
// loss = mean_r [ LSE_{c!=r}(2 z_r.z_c) - 2 z_r.z_label(r) ], z = concat(z_i,z_j) (8192x256)
// R23 = R15 verbatim (best measured: 94.2us total, k_lse ~37us = ~890 TF).
// Series verdict (R11-R22): twelve structures (LDS/global feed, barriers/none,
// ring depth 4/8, XCD pinning, hand vmcnt, 2/4/8 MFMA chains, fine quarters,
// full 256^2 template +- swizzle fix) all land k_lse 37-55us. R15 = the measured
// plain-HIP coarse-structure ceiling (~900 TF), reconfirmed 12x. The 256^2
// fine-phase template does not transfer to K=256 (8 K-tiles: no steady state;
// 128-reg acc file -> 1 block/CU -> barrier lockstep; R21/R22 both lost to R15).
// Structure: named B regs (AGPR-resident), 4-deep LDS ring via global_load_lds,
// stage 3 ahead, ONE s_barrier/phase, counted vmcnt(8), setprio, v_exp_f32
// epilogue, diag poisoned to -1e30, co-block anti-phase s_sleep stagger.

typedef __bf16 bf16x8 __attribute__((ext_vector_type(8)));
typedef __bf16 bf16x4 __attribute__((ext_vector_type(4)));
typedef float  f32x16 __attribute__((ext_vector_type(16)));

#define NPAIR 4096
#define NROW  8192
#define DIM   256
#define STRIPS 16                 // 16 column strips of 512
#define RBLK  16384               // bytes per 32-row fragment block (32*256*2)
// x = dot/T * log2(e) = dot * 2*log2(e); Z pre-scaled by sqrt(2*log2 e)
#define SQSCALE 1.6986437f
#define LN2F    0.6931471805599453f
#define M2      176.0f            // fixed LSE max (log2 units); validated R5

#define EXP2F(x) __builtin_amdgcn_exp2f(x)   // raw v_exp_f32

// ---------- kernel 1: f32 -> bf16 (pre-scaled) into Z_F + positive dots + out zero ----
__global__ __launch_bounds__(256) void k_convert(const float* __restrict__ zi,
                                                 const float* __restrict__ zj,
                                                 __bf16* __restrict__ Zf,
                                                 float* __restrict__ pos,
                                                 float* __restrict__ out) {
    const int w = threadIdx.x >> 6, lane = threadIdx.x & 63;
    const int r = blockIdx.x * 4 + w;
    if (blockIdx.x == 0 && threadIdx.x == 0) out[0] = 0.0f;
    const float4 vi = *(const float4*)(zi + r * DIM + lane * 4);
    const float4 vj = *(const float4*)(zj + r * DIM + lane * 4);
    bf16x4 bi, bj;
    bi[0] = (__bf16)(vi.x * SQSCALE); bi[1] = (__bf16)(vi.y * SQSCALE);
    bi[2] = (__bf16)(vi.z * SQSCALE); bi[3] = (__bf16)(vi.w * SQSCALE);
    bj[0] = (__bf16)(vj.x * SQSCALE); bj[1] = (__bf16)(vj.y * SQSCALE);
    bj[2] = (__bf16)(vj.z * SQSCALE); bj[3] = (__bf16)(vj.w * SQSCALE);
    // lane holds k = lane*4..+3 -> chunk t = lane>>2, half = (lane>>1)&1, inner = (lane&1)*8 B
    const int t = lane >> 2, h = (lane >> 1) & 1, inner = (lane & 1) * 8;
    char* Zb = (char*)Zf;
    *(bf16x4*)(Zb + (size_t)(r >> 5) * RBLK + t * 1024 + h * 512 + (r & 31) * 16 + inner) = bi;
    const int r2 = r + NPAIR;
    *(bf16x4*)(Zb + (size_t)(r2 >> 5) * RBLK + t * 1024 + h * 512 + (r2 & 31) * 16 + inner) = bj;
    float d = vi.x * vj.x + vi.y * vj.y + vi.z * vj.z + vi.w * vj.w;
    #pragma unroll
    for (int m = 32; m >= 1; m >>= 1) d += __shfl_xor(d, m);
    if (lane == 0) pos[r] = 2.0f * d;   // natural units
}

// ---------- kernel 2: streaming fixed-max logsumexp ----------
// grid = 32 rowblocks x 16 strips = 512 blocks of 256 thr (2 blocks/CU).
// wave w owns rows R0=rb*8+2w, R1=R0+1 (64 rows, in NAMED registers).
// A staged in 4-deep LDS ring. Odd-parity blocks anti-phased by s_sleep.
__global__ __launch_bounds__(256, 2) void k_lse(const __bf16* __restrict__ Zf,
                                                float* __restrict__ Lpart) {
    const int bx    = blockIdx.x;
    const int rb    = bx & 31;          // row block of 256 rows
    const int strip = bx >> 5;          // 0..15, cols strip*512 .. +512
    const int tid   = threadIdx.x;
    const int w     = tid >> 6;         // 0..3
    const int lane  = tid & 63, lm = lane & 31, half = lane >> 5;
    const int laneoff = half * 512 + lm * 16;
    const int R0 = rb * 8 + w * 2, R1 = R0 + 1;   // global 32-row block indices

    __shared__ __align__(16) char smem[65536];    // 4 x 16 KB A ring
    const char* Zb = (const char*)Zf;

    // ---- B rows -> 32 NAMED registers (128 VGPR, compile-time references only) ----
    const char* g0 = Zb + (size_t)R0 * RBLK + laneoff;
    const char* g1 = Zb + (size_t)R1 * RBLK + laneoff;
    #define LOADB(i) \
        bf16x8 B0_##i = *(const bf16x8*)(g0 + (i) * 1024); \
        bf16x8 B1_##i = *(const bf16x8*)(g1 + (i) * 1024);
    LOADB(0)  LOADB(1)  LOADB(2)  LOADB(3)
    LOADB(4)  LOADB(5)  LOADB(6)  LOADB(7)
    LOADB(8)  LOADB(9)  LOADB(10) LOADB(11)
    LOADB(12) LOADB(13) LOADB(14) LOADB(15)
    #undef LOADB

    const char* Acol = Zb + (size_t)strip * 16 * RBLK;   // strip's 16 col-RBLKs

    // async stage of one col-RBLK (16 KB): 256 thr x 4 x 16 B, linear LDS dest
    #define STAGE(bufsel, phidx) do {                                              \
        const char* _s = Acol + (size_t)(phidx) * RBLK + tid * 16;                 \
        char*       _d = smem + (bufsel) * 16384 + tid * 16;                       \
        _Pragma("unroll")                                                          \
        for (int _q = 0; _q < 4; _q++)                                             \
            __builtin_amdgcn_global_load_lds(                                      \
                (const __attribute__((address_space(1))) unsigned int*)(_s + _q * 4096), \
                (__attribute__((address_space(3))) unsigned int*)(_d + _q * 4096), \
                16, 0, 0);                                                         \
    } while (0)

    float l0 = 0.0f, l1 = 0.0f;

    // one MFMA K-step: a-frag from LDS (compile-time offset), named B refs.
    #define MSTEP(i) {                                                             \
        bf16x8 a_ = *(const bf16x8*)(Ab + (i) * 1024);                             \
        acc0 = __builtin_amdgcn_mfma_f32_32x32x16_bf16(a_, B0_##i, acc0, 0, 0, 0); \
        acc1 = __builtin_amdgcn_mfma_f32_32x32x16_bf16(a_, B1_##i, acc1, 0, 0, 0); \
    }

    // one phase: wait own stage-ph loads (counted), barrier, issue stage ph+3 into
    // the just-freed buffer, 32 MFMA (fully named), diag poison, v_exp_f32 epilogue.
    #define PHASE_BODY(PH, WAITSTR, DO_STAGE) do {                                 \
        asm volatile("s_waitcnt vmcnt(" WAITSTR ")" ::: "memory");                 \
        __builtin_amdgcn_s_barrier();                                              \
        asm volatile("" ::: "memory");                                             \
        if (DO_STAGE) STAGE(((PH) + 3) & 3, (PH) + 3);                             \
        const char* Ab = smem + ((PH) & 3) * 16384 + laneoff;                      \
        f32x16 acc0 = (f32x16)(0.0f);                                              \
        f32x16 acc1 = (f32x16)(0.0f);                                              \
        __builtin_amdgcn_s_setprio(1);                                             \
        MSTEP(0)  MSTEP(1)  MSTEP(2)  MSTEP(3)                                     \
        MSTEP(4)  MSTEP(5)  MSTEP(6)  MSTEP(7)                                     \
        MSTEP(8)  MSTEP(9)  MSTEP(10) MSTEP(11)                                    \
        MSTEP(12) MSTEP(13) MSTEP(14) MSTEP(15)                                    \
        __builtin_amdgcn_s_setprio(0);                                             \
        const int cb = strip * 16 + (PH);                                          \
        if (cb == R0) {   /* wave-uniform: acc0 tile holds the diagonal */         \
            _Pragma("unroll")                                                      \
            for (int rg = 0; rg < 16; rg++) {                                      \
                const int cl = (rg & 3) + 8 * (rg >> 2) + 4 * half;                \
                acc0[rg] = (cl == lm) ? -1e30f : acc0[rg];                         \
            }                                                                      \
        }                                                                          \
        if (cb == R1) {                                                            \
            _Pragma("unroll")                                                      \
            for (int rg = 0; rg < 16; rg++) {                                      \
                const int cl = (rg & 3) + 8 * (rg >> 2) + 4 * half;                \
                acc1[rg] = (cl == lm) ? -1e30f : acc1[rg];                         \
            }                                                                      \
        }                                                                          \
        float p0 = 0.0f, p1 = 0.0f, q0 = 0.0f, q1 = 0.0f;                          \
        _Pragma("unroll")                                                          \
        for (int rg = 0; rg < 16; rg += 2) {                                       \
            p0 += EXP2F(acc0[rg]     - M2);                                        \
            p1 += EXP2F(acc0[rg + 1] - M2);                                        \
            q0 += EXP2F(acc1[rg]     - M2);                                        \
            q1 += EXP2F(acc1[rg + 1] - M2);                                        \
        }                                                                          \
        l0 += p0 + p1;                                                             \
        l1 += q0 + q1;                                                             \
    } while (0)

    // prologue: 3 stages in flight (12 loads/thread)
    STAGE(0, 0);
    STAGE(1, 1);
    STAGE(2, 2);

    // ANTI-PHASE: odd-parity blocks sleep ~2880 cyc (half a phase) so co-resident
    // block pairs interleave their LDS/MFMA bursts with the partner's epilogue.
    // Parity differs for pairings (2k,2k+1) and (k,k+256). Timing-only; no
    // correctness impact (stages already issued; vmcnt unaffected by s_sleep).
    if ((bx ^ (bx >> 8)) & 1) __builtin_amdgcn_s_sleep(45);

    for (int ph = 0; ph < 14; ph++) {
        PHASE_BODY(ph, "8", ph < 13);   // steady state: keep 2 stages (8 loads) flying
    }
    PHASE_BODY(14, "4", 0);
    PHASE_BODY(15, "0", 0);

    #undef PHASE_BODY
    #undef MSTEP
    #undef STAGE

    // merge k-halves (lane <-> lane^32: same row, disjoint col subsets) by ADD
    l0 += __shfl_xor(l0, 32);
    l1 += __shfl_xor(l1, 32);
    if (half == 0) {
        Lpart[strip * NROW + R0 * 32 + lm] = l0;
        Lpart[strip * NROW + R1 * 32 + lm] = l1;
    }
}

// ---------- kernel 3: merge strips, per-row loss, atomic mean ----------
__global__ __launch_bounds__(256) void k_final(const float* __restrict__ Lpart,
                                               const float* __restrict__ pos,
                                               float* __restrict__ out) {
    __shared__ float red[256];
    const int t = threadIdx.x;
    const int r = blockIdx.x * 256 + t;
    float l = 0.0f;
    #pragma unroll
    for (int s = 0; s < STRIPS; s++) l += Lpart[s * NROW + r];
    const float lse = (M2 + __builtin_log2f(l)) * LN2F;   // natural-log LSE
    red[t] = lse - pos[r & (NPAIR - 1)];
    __syncthreads();
    for (int ofs = 128; ofs > 0; ofs >>= 1) {
        if (t < ofs) red[t] += red[t + ofs];
        __syncthreads();
    }
    if (t == 0) atomicAdd(out, red[0] / (float)NROW);
}

extern "C" void kernel_launch(void* const* d_in, const int* in_sizes, int n_in,
                              void* d_out, int out_size, void* d_ws, size_t ws_size,
                              hipStream_t stream) {
    const float* zi = (const float*)d_in[0];
    const float* zj = (const float*)d_in[1];
    __bf16* Zf   = (__bf16*)d_ws;                       // 4 MB fragment-ready
    float* pos   = (float*)((char*)d_ws + (size_t)NROW * DIM * 2);
    float* Lpart = pos + NPAIR;                         // 16 x 8192 floats

    k_convert<<<NPAIR / 4, 256, 0, stream>>>(zi, zj, Zf, pos, (float*)d_out);
    k_lse<<<32 * STRIPS, 256, 0, stream>>>(Zf, Lpart);
    k_final<<<NROW / 256, 256, 0, stream>>>(Lpart, pos, (float*)d_out);
}